// Round 9
// baseline (10222.474 us; speedup 1.0000x reference)
//
#include <hip/hip_runtime.h>

// ---------------------------------------------------------------------------
// 2-layer GRU, T=512, B=64, I=H=512, fp32. Persistent cooperative kernel:
// 256 WGs (1/CU) x 512 threads (8 waves), layers wavefront-pipelined
// (513 grid-steps).
// Round 9: WEIGHTS STATIONARY IN LDS.
//  - Each WG stages its 48 KB weight slice (12 rows x 2 sides x 512 K fp32)
//    into LDS once; the inner loop reads weights via ds_read_b128 at
//    wave-uniform addresses (broadcast, conflict-free). This removes 49 KB
//    per WG-step of wave-uniform weight loads from the vector-memory/L1
//    port — the shared resource that r6/r7/r8 showed parallelism cannot
//    hide (ILP, TLP, occupancy all null).
//  - inner product as f32x2 + __builtin_elementwise_fma -> llvm.fma.v2f32
//    -> v_pk_fma_f32 if gfx950 packs it (2x FMA issue); plain 2x v_fma if
//    not (no risk).
//  - everything else = round 5 (best): fresh-address h ring in ws, h2->out,
//    producers write-through sc0 sc1, consumers cached, entry acquire fence,
//    packed-flag all-poll barrier.
// ---------------------------------------------------------------------------

typedef float f32x4 __attribute__((ext_vector_type(4)));
typedef float f32x2 __attribute__((ext_vector_type(2)));
typedef unsigned u32x4 __attribute__((ext_vector_type(4)));

#define GB_B 64
#define GB_H 512
#define GB_K 512
#define GB_G 1536
#define GB_T 512
#define NWG 256
#define NTHR 512
#define BH (GB_B * GB_H)  // one step-slab: 32768 floats = 131 KB

// float-word offsets inside ws
#define OFF_FLAGS 0     // 256 packed u32 flags (1 KB)
#define OFF_RING1 1024  // 512 slabs of BH floats = 67.1 MB

// ---- coherence helpers ----------------------------------------------------
__device__ __forceinline__ void st_coh_f4(float* p, f32x4 v) {
  asm volatile("global_store_dwordx4 %0, %1, off sc0 sc1" ::"v"(p), "v"(v)
               : "memory");
}
__device__ __forceinline__ void st_coh_u32(unsigned* p, unsigned v) {
  asm volatile("global_store_dword %0, %1, off sc0 sc1" ::"v"(p), "v"(v)
               : "memory");
}
// 16B coherent load of 4 packed flags, NO wait — caller manages vmcnt.
#define LDC4U(dst, addr)                                  \
  asm volatile("global_load_dwordx4 %0, %1, off sc0 sc1" \
               : "=v"(dst)                                \
               : "v"(addr))

__global__ void gru_init(float* __restrict__ ws) {
  unsigned* fl = (unsigned*)(ws + OFF_FLAGS);
  st_coh_u32(&fl[threadIdx.x], 0u);  // 1 block x 256 threads
}

__global__ __launch_bounds__(NTHR, 1) void gru_persist(
    const float* __restrict__ x, const float* __restrict__ h0,
    const float* __restrict__ w_ih, const float* __restrict__ w_hh,
    const float* __restrict__ b_ih, const float* __restrict__ b_hh,
    float* __restrict__ out, float* __restrict__ ws) {
  __shared__ float wlds[2][12][GB_K];  // 48 KB stationary weights
  __shared__ float part[8][12][GB_B];  // 24 KB cross-wave partials
  __shared__ float sh_h[GB_B][4];      // 1 KB transpose tile

  const int tid = threadIdx.x;
  const int lane = tid & 63;  // batch row
  const int wg = blockIdx.x;
  const int layer = wg >> 7;       // 0 = first GRU layer, 1 = second
  const int j0 = (wg & 127) << 2;  // 4 hidden cols per WG
  const int wave = __builtin_amdgcn_readfirstlane(tid >> 6);
  const int side = wave >> 2;         // 0 = input-side, 1 = hidden-side
  const int kbase = (wave & 3) << 7;  // K-quarter * 128

  unsigned* flags = (unsigned*)(ws + OFF_FLAGS);
  float* ring1 = ws + OFF_RING1;  // h1_t slabs, t = 0..511

  // ---- stage this WG's weight slice into LDS (once) ----
  {
    const float* Wmat = (side ? w_hh : w_ih) + (size_t)layer * GB_G * GB_K;
#pragma unroll
    for (int r = 0; r < 12; ++r) {
      const int gate = r >> 2, jj = r & 3;
      const float* src =
          Wmat + (size_t)(gate * GB_H + j0 + jj) * GB_K + kbase + lane * 2;
      *(f32x2*)&wlds[side][r][kbase + lane * 2] = *(const f32x2*)src;
    }
  }

  // Epilogue state: biases + own-column running h in registers (waves 0-3).
  float bx[3] = {0.f, 0.f, 0.f}, bh[3] = {0.f, 0.f, 0.f};
  float hreg = 0.f;
  if (wave < 4) {
    const int j = j0 + wave;
#pragma unroll
    for (int g = 0; g < 3; ++g) {
      bx[g] = b_ih[layer * GB_G + g * GB_H + j];
      bh[g] = b_hh[layer * GB_G + g * GB_H + j];
    }
    hreg = h0[((size_t)layer * GB_B + lane) * GB_H + j];
  }

  // Drop stale L1/L2 lines (poison / previous replay) before cached reads of
  // ring1/out slabs; also covers the weight staging before first use.
  __builtin_amdgcn_fence(__ATOMIC_ACQUIRE, "agent");
  __syncthreads();

  const float* wl = &wlds[side][0][kbase];  // row stride GB_K floats

  for (int s = 0; s <= GB_T; ++s) {
    const int t = layer ? s - 1 : s;
    const bool active = layer ? (s >= 1) : (s < GB_T);

    if (active) {
      // A-operand base: mutable slabs are fresh-address -> cached loads ok.
      const float* Abase;
      if (layer == 0)
        Abase = side ? (t ? ring1 + (size_t)(t - 1) * BH : h0)
                     : (x + (size_t)t * BH);
      else
        Abase = side ? (t ? out + (size_t)(t - 1) * BH : h0 + BH)
                     : (ring1 + (size_t)t * BH);
      const float* Arow = Abase + lane * GB_K + kbase;

      f32x2 acc2[12];
#pragma unroll
      for (int c = 0; c < 12; ++c) acc2[c] = (f32x2)(0.f);

#pragma unroll
      for (int u = 0; u < 32; ++u) {
        const f32x4 a = ((const f32x4*)Arow)[u];
        const f32x2 a01 = a.xy, a23 = a.zw;
#pragma unroll
        for (int r = 0; r < 12; ++r) {
          const f32x4 w = *(const f32x4*)(wl + r * GB_K + u * 4);
          acc2[r] = __builtin_elementwise_fma(a01, w.xy, acc2[r]);
          acc2[r] = __builtin_elementwise_fma(a23, w.zw, acc2[r]);
        }
      }
#pragma unroll
      for (int c = 0; c < 12; ++c)
        part[wave][c][lane] = acc2[c].x + acc2[c].y;
    }
    __syncthreads();

    if (active && wave < 4) {  // epilogue: wave w handles col j = j0 + w
      float X[3], Hs[3];
#pragma unroll
      for (int gate = 0; gate < 3; ++gate) {
        const int c = gate * 4 + wave;
        X[gate] = part[0][c][lane] + part[1][c][lane] + part[2][c][lane] +
                  part[3][c][lane] + bx[gate];
        Hs[gate] = part[4][c][lane] + part[5][c][lane] + part[6][c][lane] +
                   part[7][c][lane] + bh[gate];
      }
      const float r = 1.f / (1.f + __expf(-(X[0] + Hs[0])));
      const float z = 1.f / (1.f + __expf(-(X[1] + Hs[1])));
      const float n = tanhf(X[2] + r * Hs[2]);
      const float hnew = (1.f - z) * n + z * hreg;
      hreg = hnew;
      sh_h[lane][wave] = hnew;
    }
    __syncthreads();

    // Wave 0: store the 64x4 h tile (write-through), then grid barrier.
    if (tid < 64) {
      if (active) {
        const f32x4 hv = *(const f32x4*)&sh_h[lane][0];
        float* dst = (layer ? out : ring1) + (size_t)t * BH;
        st_coh_f4(dst + lane * GB_H + j0, hv);
      }
      if (s < GB_T) {
        asm volatile("s_waitcnt vmcnt(0)" ::: "memory");  // h stores at L3
        if (tid == 0) st_coh_u32(&flags[wg], (unsigned)(s + 1));
        const unsigned tgt = (unsigned)(s + 1);
        const unsigned* fp = flags + lane * 4;
        for (;;) {
          u32x4 f;
          LDC4U(f, fp);
          asm volatile("s_waitcnt vmcnt(0)" ::: "memory");
          const int ok =
              (f.x >= tgt) && (f.y >= tgt) && (f.z >= tgt) && (f.w >= tgt);
          if (__all(ok)) break;
          __builtin_amdgcn_s_sleep(1);
        }
      }
    }
    __syncthreads();
  }
}

extern "C" void kernel_launch(void* const* d_in, const int* in_sizes, int n_in,
                              void* d_out, int out_size, void* d_ws,
                              size_t ws_size, hipStream_t stream) {
  const float* x = (const float*)d_in[0];
  const float* h0 = (const float*)d_in[1];
  const float* w_ih = (const float*)d_in[2];
  const float* w_hh = (const float*)d_in[3];
  const float* b_ih = (const float*)d_in[4];
  const float* b_hh = (const float*)d_in[5];
  float* out = (float*)d_out;
  float* ws = (float*)d_ws;

  gru_init<<<1, 256, 0, stream>>>(ws);

  void* args[] = {(void*)&x,    (void*)&h0,   (void*)&w_ih, (void*)&w_hh,
                  (void*)&b_ih, (void*)&b_hh, (void*)&out,  (void*)&ws};
  (void)hipLaunchCooperativeKernel((const void*)gru_persist, dim3(NWG),
                                   dim3(NTHR), args, 0, stream);
}